// Round 4
// baseline (236.785 us; speedup 1.0000x reference)
//
#include <hip/hip_runtime.h>
#include <math.h>

// Problem constants
#define BB 8
#define TT 2048
#define DM 1024
#define DH 128
#define US unsigned short

typedef short s8v __attribute__((ext_vector_type(8)));
typedef US us8 __attribute__((ext_vector_type(8)));
typedef float f4v __attribute__((ext_vector_type(4)));

__device__ __forceinline__ US f2bf(float f) {
  uint u = __float_as_uint(f);
  uint r = (u + 0x7fffu + ((u >> 16) & 1u)) >> 16;  // RNE
  return (US)r;
}
__device__ __forceinline__ float bf2f(US h) {
  return __uint_as_float(((uint)h) << 16);
}
__device__ __forceinline__ void cvt4(const float4 v, uint2& h, uint2& lo) {
  US h0 = f2bf(v.x), h1 = f2bf(v.y), h2 = f2bf(v.z), h3 = f2bf(v.w);
  US l0 = f2bf(v.x - bf2f(h0)), l1 = f2bf(v.y - bf2f(h1)),
     l2 = f2bf(v.z - bf2f(h2)), l3 = f2bf(v.w - bf2f(h3));
  h = make_uint2((uint)h0 | ((uint)h1 << 16), (uint)h2 | ((uint)h3 << 16));
  lo = make_uint2((uint)l0 | ((uint)l1 << 16), (uint)l2 | ((uint)l3 << 16));
}

// ============================================================================
// Kernel 1: fused QKV projection via split-bf16 MFMA (hi*hi+hi*lo+lo*hi),
// + RoPE + L2-norm * sqk for q,k.  Outputs (all bf16):
//   qbf, kbf row-major [b*T][128]; vbT hi/lo TRANSPOSED [b][dv=128][t=2048]
//   (pre-transposed + pre-split so K2's V staging is a straight copy into
//    the MFMA B-frag layout — no LDS transpose ever needed).
// ============================================================================
#define XHI 0
#define XLO 2048
#define WHI 4096
#define WLO 16384
#define NEG_L2B_64 -0.20762050593549395f  // -log2(10000)/64

__global__ __launch_bounds__(512) void qkv_rope_norm(
    const float* __restrict__ x, const float* __restrict__ W,
    const float* __restrict__ sqk, US* __restrict__ qbf, US* __restrict__ kbf,
    US* __restrict__ vhT, US* __restrict__ vlT) {
  __shared__ __align__(16) US smem_u[28672];  // 56 KB
  const int tid = threadIdx.x;
  const int m0 = blockIdx.x * 64;

  // ---- staging ids (coalesced global: 8 lanes cover 128B of one row) ----
  const int srow = tid >> 3;  // 0..63
  const int c4 = tid & 7;     // float4-column within the 32-wide K chunk
  const int k8s = c4 >> 1, half = c4 & 1;
  const float* xg = x + (size_t)(m0 + srow) * DM + (c4 << 2);
  const float* wg = W + (size_t)srow * DM + (c4 << 2);
  const int xeo = (k8s * 64 + srow) * 8 + half * 4;  // ushort offset

  // ---- mfma ids ----
  const int l = tid & 63, w = tid >> 6;
  const int wm = w >> 2, wn = w & 3;
  const int lr = l & 15, k8l = l >> 4;
  const int arow = wm * 32;

  f4v acc[2][6];
#pragma unroll
  for (int r = 0; r < 2; ++r)
#pragma unroll
    for (int c = 0; c < 6; ++c) acc[r][c] = (f4v)(0.f);

  // prefetch chunk 0
  float4 gx = *(const float4*)(xg);
  float4 gw[6];
#pragma unroll
  for (int i = 0; i < 6; ++i) gw[i] = *(const float4*)(wg + (size_t)i * 64 * DM);

  for (int kc = 0; kc < 32; ++kc) {
    __syncthreads();  // prior compute finished reading LDS (no-op iter 0)
    {
      uint2 h, lo;
      cvt4(gx, h, lo);
      *(uint2*)&smem_u[XHI + xeo] = h;
      *(uint2*)&smem_u[XLO + xeo] = lo;
#pragma unroll
      for (int i = 0; i < 6; ++i) {
        int weo = (k8s * 384 + srow + 64 * i) * 8 + half * 4;
        cvt4(gw[i], h, lo);
        *(uint2*)&smem_u[WHI + weo] = h;
        *(uint2*)&smem_u[WLO + weo] = lo;
      }
    }
    {
      int kn = (kc < 31) ? (kc + 1) * 32 : 0;  // last iter: dummy reload
      gx = *(const float4*)(xg + kn);
#pragma unroll
      for (int i = 0; i < 6; ++i)
        gw[i] = *(const float4*)(wg + (size_t)i * 64 * DM + kn);
    }
    __syncthreads();
    // compute: 36 MFMAs
    s8v axh[2], axl[2];
#pragma unroll
    for (int r = 0; r < 2; ++r) {
      int ao = (k8l * 64 + arow + r * 16 + lr) * 8;
      axh[r] = *(const s8v*)&smem_u[XHI + ao];
      axl[r] = *(const s8v*)&smem_u[XLO + ao];
    }
#pragma unroll
    for (int c = 0; c < 6; ++c) {
      int bo = (k8l * 384 + wn * 96 + c * 16 + lr) * 8;
      s8v bh = *(const s8v*)&smem_u[WHI + bo];
      s8v bl = *(const s8v*)&smem_u[WLO + bo];
#pragma unroll
      for (int r = 0; r < 2; ++r) {
        acc[r][c] =
            __builtin_amdgcn_mfma_f32_16x16x32_bf16(axh[r], bh, acc[r][c], 0, 0, 0);
        acc[r][c] =
            __builtin_amdgcn_mfma_f32_16x16x32_bf16(axl[r], bh, acc[r][c], 0, 0, 0);
        acc[r][c] =
            __builtin_amdgcn_mfma_f32_16x16x32_bf16(axh[r], bl, acc[r][c], 0, 0, 0);
      }
    }
  }

  // ---- epilogue: per 128-col part: restage to row-contiguous LDS ----
  __syncthreads();
  float* buf = (float*)smem_u;  // [64][132] floats (33.8 KB)
  const int prow = tid >> 3, sub = tid & 7;
  const int q4row = (l >> 4) * 4;
  const int bq = m0 >> 11;       // batch
  const int t0 = m0 & (TT - 1);  // position base
  const float t_pos = (float)(t0 + prow);

#pragma unroll
  for (int p = 0; p < 3; ++p) {
    // write phase: frags whose col-base falls in [128p, 128p+128)
#pragma unroll
    for (int c = 0; c < 6; ++c) {
      int nbase = wn * 96 + c * 16;
      if ((nbase >> 7) == p) {
        int coloff = nbase & 127;
#pragma unroll
        for (int r = 0; r < 2; ++r)
#pragma unroll
          for (int q = 0; q < 4; ++q)
            buf[(arow + r * 16 + q4row + q) * 132 + coloff + lr] = acc[r][c][q];
      }
    }
    __syncthreads();
    if (p == 2) {
      // v: transpose-store as split bf16 hi/lo into vbT [b][dv][t]
      const int dv = tid >> 2;
      const int rr = (tid & 3) * 16;
      us8 h0, h1, l0, l1;
#pragma unroll
      for (int i = 0; i < 8; ++i) {
        float va = buf[(rr + i) * 132 + dv];
        float vb2 = buf[(rr + 8 + i) * 132 + dv];
        US ha = f2bf(va), hb = f2bf(vb2);
        h0[i] = ha; h1[i] = hb;
        l0[i] = f2bf(va - bf2f(ha));
        l1[i] = f2bf(vb2 - bf2f(hb));
      }
      size_t base = ((size_t)bq * DH + dv) * TT + t0 + rr;
      *(us8*)(vhT + base) = h0;
      *(us8*)(vhT + base + 8) = h1;
      *(us8*)(vlT + base) = l0;
      *(us8*)(vlT + base + 8) = l1;
    } else {
      // q or k: RoPE + L2-norm + *sqk, store bf16 row-major
      const float* br = &buf[prow * 132 + sub * 16];
      float4 a0 = *(const float4*)(br + 0);
      float4 a1 = *(const float4*)(br + 4);
      float4 a2 = *(const float4*)(br + 8);
      float4 a3 = *(const float4*)(br + 12);
      float vals[16] = {a0.x, a0.y, a0.z, a0.w, a1.x, a1.y, a1.z, a1.w,
                        a2.x, a2.y, a2.z, a2.w, a3.x, a3.y, a3.z, a3.w};
      float ov[16];
      float ss = 0.f;
#pragma unroll
      for (int j = 0; j < 16; ++j) {
        float val = vals[j];
        float partner = __shfl_xor(val, 4);  // col +/- 64 lives in lane sub^4
        int fi = ((sub & 3) * 16) + j;       // freq index = col % 64
        float ang = t_pos * exp2f((float)fi * NEG_L2B_64);
        float sn, cs;
        sincosf(ang, &sn, &cs);
        float rot = (sub < 4) ? -partner : partner;
        float o = fmaf(val, cs, rot * sn);
        ov[j] = o;
        ss = fmaf(o, o, ss);
      }
      ss += __shfl_xor(ss, 1);
      ss += __shfl_xor(ss, 2);
      ss += __shfl_xor(ss, 4);
      float rn = 1.0f / sqrtf(ss);
      const float* sqp = sqk + sub * 16;
      US* dst = (p == 0 ? qbf : kbf) + (size_t)(m0 + prow) * DH + sub * 16;
      us8 o0, o1;
#pragma unroll
      for (int j = 0; j < 8; ++j) {
        o0[j] = f2bf(ov[j] * rn * sqp[j]);
        o1[j] = f2bf(ov[8 + j] * rn * sqp[8 + j]);
      }
      *(us8*)dst = o0;
      *(us8*)(dst + 8) = o1;
    }
    __syncthreads();
  }
}

// ============================================================================
// Kernel 2: causal flash attention, bf16 MFMA, K-range-split for balance.
//   256 thr = 4 waves; wave w owns q-rows w*16..w*16+15 of the 64-row tile.
//   QK^T: A=Q [d8][row][8] (XOR-swizzled), B=K same layout -> S in C-frag
//   (row=(l>>4)*4+q, col=l&15). Softmax in-register (16-lane shfl reduce).
//   P split hi/lo -> LDS [64][136] us; PV = Ph*Vh + Pl*Vh + Ph*Vl (3-term,
//   ~2e-5 accuracy). V staged straight from pre-transposed global.
//   P rows are per-wave self-contained -> only 2 barriers per K-tile.
//   Unnormalized partial O + (m,l) to ws; merge kernel combines.
// ============================================================================
#define BQ 64
#define BK 64
#define SCALE 32.0f  // sqrt(d_model=1024)
#define NLOC 80
#define NJOB (NLOC * BB)
// LDS offsets (ushort units)
#define QSO 0
#define KSO 8192
#define VHO 16384
#define VLO 24576
#define PHO 32768
#define PLO 41472
#define SMEM_US 50176  // 100352 bytes dynamic LDS

__device__ __forceinline__ int slot_base(int qt) {
  if (qt < 8) return qt;
  if (qt < 16) return 8 + 2 * (qt - 8);
  if (qt < 24) return 24 + 3 * (qt - 16);
  return 48 + 4 * (qt - 24);
}

__global__ __launch_bounds__(256) void attn_causal(
    const US* __restrict__ qbf, const US* __restrict__ kbf,
    const US* __restrict__ vhT, const US* __restrict__ vlT,
    float* __restrict__ pO, float* __restrict__ pm, float* __restrict__ pl) {
  extern __shared__ US sm[];
  const int tid = threadIdx.x;
  // ---- job decode (heavy-first) ----
  const int bi = blockIdx.x;
  const int b = bi & 7;
  const int local = bi >> 3;
  int qt, s;
  if (local < 32) {
    qt = 31 - (local >> 2); s = local & 3;
  } else if (local < 56) {
    int l2 = local - 32; qt = 23 - l2 / 3; s = l2 - (l2 / 3) * 3;
  } else if (local < 72) {
    int l2 = local - 56; qt = 15 - (l2 >> 1); s = l2 & 1;
  } else {
    qt = 7 - (local - 72); s = 0;
  }
  const int S = 1 + (qt >> 3);
  const int nk = qt + 1;
  const int kt0 = (s * nk) / S;
  const int kt1 = ((s + 1) * nk) / S;
  const int slot = b * NLOC + slot_base(qt) + s;

  const int ln = tid & 63, w = tid >> 6;
  const int wrow = w * 16;
  const int l15 = ln & 15, l4 = ln >> 4;

  // ---- stage Q tile: [d8][row^(d8&7)][8] ----
  {
    const int d8 = tid & 15, r0 = tid >> 4;
    const US* src = qbf + ((size_t)b * TT + (size_t)qt * BQ) * DH + d8 * 8;
#pragma unroll
    for (int p = 0; p < 4; ++p) {
      int r = r0 + p * 16;
      us8 v = *(const us8*)(src + (size_t)r * DH);
      *(us8*)&sm[QSO + (d8 * 64 + (r ^ (d8 & 7))) * 8] = v;
    }
  }

  float m[4], lsum[4];
  f4v o[8];
#pragma unroll
  for (int q = 0; q < 4; ++q) { m[q] = -1e30f; lsum[q] = 0.f; }
#pragma unroll
  for (int c8 = 0; c8 < 8; ++c8) o[c8] = (f4v)(0.f);

  for (int kt = kt0; kt < kt1; ++kt) {
    __syncthreads();  // prev iter's frag reads done (also covers Q staging)
    // ---- stage K tile ----
    {
      const int d8 = tid & 15, r0 = tid >> 4;
      const US* src = kbf + ((size_t)b * TT + (size_t)kt * BK) * DH + d8 * 8;
#pragma unroll
      for (int p = 0; p < 4; ++p) {
        int r = r0 + p * 16;
        us8 v = *(const us8*)(src + (size_t)r * DH);
        *(us8*)&sm[KSO + (d8 * 64 + (r ^ (d8 & 7))) * 8] = v;
      }
    }
    // ---- stage V tiles (straight copy; already transposed + split) ----
    {
      const int kv8 = tid & 7, dv0 = tid >> 3;
      const size_t gb = (size_t)b * DH * TT + (size_t)kt * BK + kv8 * 8;
#pragma unroll
      for (int p = 0; p < 4; ++p) {
        int dv = dv0 + p * 32;
        us8 vh = *(const us8*)(vhT + gb + (size_t)dv * TT);
        us8 vl = *(const us8*)(vlT + gb + (size_t)dv * TT);
        *(us8*)&sm[VHO + (kv8 * 128 + dv) * 8] = vh;
        *(us8*)&sm[VLO + (kv8 * 128 + dv) * 8] = vl;
      }
    }
    __syncthreads();

    // ---- QK^T: 16 MFMA ----
    f4v sfr[4];
#pragma unroll
    for (int c = 0; c < 4; ++c) sfr[c] = (f4v)(0.f);
#pragma unroll
    for (int ks = 0; ks < 4; ++ks) {
      const int d8 = ks * 4 + l4;
      const int perm = (l15 ^ (d8 & 7));
      s8v a = *(const s8v*)&sm[QSO + (d8 * 64 + wrow + perm) * 8];
#pragma unroll
      for (int c = 0; c < 4; ++c) {
        s8v bk = *(const s8v*)&sm[KSO + (d8 * 64 + c * 16 + perm) * 8];
        sfr[c] = __builtin_amdgcn_mfma_f32_16x16x32_bf16(a, bk, sfr[c], 0, 0, 0);
      }
    }

    // ---- online softmax (rows wrow+l4*4+q; cols c*16+l15) + P write ----
    const bool diag = (kt == qt);
    float alpha[4];
#pragma unroll
    for (int q = 0; q < 4; ++q) {
      const int rowg = qt * BQ + wrow + l4 * 4 + q;
      float st[4];
      float mx = -1e30f;
#pragma unroll
      for (int c = 0; c < 4; ++c) {
        float sv = sfr[c][q] * SCALE;
        if (diag && (kt * BK + c * 16 + l15 > rowg)) sv = -1e30f;
        st[c] = sv;
        mx = fmaxf(mx, sv);
      }
      mx = fmaxf(mx, __shfl_xor(mx, 1));
      mx = fmaxf(mx, __shfl_xor(mx, 2));
      mx = fmaxf(mx, __shfl_xor(mx, 4));
      mx = fmaxf(mx, __shfl_xor(mx, 8));
      float mn = fmaxf(m[q], mx);
      float a = __expf(m[q] - mn);
      float rs = 0.f;
      const int prow_off = (wrow + l4 * 4 + q) * 136 + l15;
#pragma unroll
      for (int c = 0; c < 4; ++c) {
        float pv = __expf(st[c] - mn);
        rs += pv;
        US ph = f2bf(pv);
        sm[PHO + prow_off + c * 16] = ph;
        sm[PLO + prow_off + c * 16] = f2bf(pv - bf2f(ph));
      }
      rs += __shfl_xor(rs, 1);
      rs += __shfl_xor(rs, 2);
      rs += __shfl_xor(rs, 4);
      rs += __shfl_xor(rs, 8);
      lsum[q] = lsum[q] * a + rs;
      m[q] = mn;
      alpha[q] = a;
    }

    // ---- rescale O, then PV (P rows are wave-local: no barrier needed) ----
#pragma unroll
    for (int c8 = 0; c8 < 8; ++c8)
#pragma unroll
      for (int q = 0; q < 4; ++q) o[c8][q] *= alpha[q];

#pragma unroll
    for (int ks = 0; ks < 2; ++ks) {
      const int aoff = (wrow + l15) * 136 + ks * 32 + l4 * 8;
      s8v pa = *(const s8v*)&sm[PHO + aoff];
      s8v pb = *(const s8v*)&sm[PLO + aoff];
      const int kv8 = ks * 4 + l4;
#pragma unroll
      for (int c8 = 0; c8 < 8; ++c8) {
        const int vo = (kv8 * 128 + c8 * 16 + l15) * 8;
        s8v vh = *(const s8v*)&sm[VHO + vo];
        s8v vl = *(const s8v*)&sm[VLO + vo];
        o[c8] = __builtin_amdgcn_mfma_f32_16x16x32_bf16(pa, vh, o[c8], 0, 0, 0);
        o[c8] = __builtin_amdgcn_mfma_f32_16x16x32_bf16(pb, vh, o[c8], 0, 0, 0);
        o[c8] = __builtin_amdgcn_mfma_f32_16x16x32_bf16(pa, vl, o[c8], 0, 0, 0);
      }
    }
  }

  // ---- epilogue: unnormalized partial O + per-row m,l ----
  float* ob = pO + (size_t)slot * (BQ * DH);
#pragma unroll
  for (int q = 0; q < 4; ++q) {
    const int r = wrow + l4 * 4 + q;
#pragma unroll
    for (int c8 = 0; c8 < 8; ++c8)
      ob[(size_t)r * DH + c8 * 16 + l15] = o[c8][q];
  }
  if (l15 == 0) {
#pragma unroll
    for (int q = 0; q < 4; ++q) {
      pm[slot * BQ + wrow + l4 * 4 + q] = m[q];
      pl[slot * BQ + wrow + l4 * 4 + q] = lsum[q];
    }
  }
}

// ============================================================================
// Kernel 3: merge partials (log-sum-exp weighted combine).
// ============================================================================
__global__ __launch_bounds__(256) void attn_merge(
    const float* __restrict__ pO, const float* __restrict__ pm,
    const float* __restrict__ pl, float* __restrict__ out) {
  const int g4 = blockIdx.x * 256 + threadIdx.x;
  const int row = g4 >> 5;
  const int c4 = g4 & 31;
  const int t = row & (TT - 1);
  const int qt = t >> 6;
  const int rloc = t & 63;
  const int b = row >> 11;
  const int S = 1 + (qt >> 3);
  const int base = b * NLOC + slot_base(qt);

  float ms[4], ls[4];
  float mstar = -1e30f;
#pragma unroll
  for (int s = 0; s < 4; ++s) {
    if (s < S) {
      ms[s] = pm[(base + s) * BQ + rloc];
      ls[s] = pl[(base + s) * BQ + rloc];
      mstar = fmaxf(mstar, ms[s]);
    }
  }
  float4 acc = make_float4(0.f, 0.f, 0.f, 0.f);
  float L = 0.f;
#pragma unroll
  for (int s = 0; s < 4; ++s) {
    if (s < S) {
      float wgt = __expf(ms[s] - mstar);
      L += wgt * ls[s];
      float4 o4 = *(const float4*)(pO + (size_t)(base + s) * (BQ * DH) +
                                   (size_t)rloc * DH + (c4 << 2));
      acc.x = fmaf(wgt, o4.x, acc.x);
      acc.y = fmaf(wgt, o4.y, acc.y);
      acc.z = fmaf(wgt, o4.z, acc.z);
      acc.w = fmaf(wgt, o4.w, acc.w);
    }
  }
  float inv = 1.0f / L;
  *(float4*)(out + (size_t)row * DH + (c4 << 2)) =
      make_float4(acc.x * inv, acc.y * inv, acc.z * inv, acc.w * inv);
}

// ============================================================================
extern "C" void kernel_launch(void* const* d_in, const int* in_sizes, int n_in,
                              void* d_out, int out_size, void* d_ws, size_t ws_size,
                              hipStream_t stream) {
  const float* x = (const float*)d_in[0];    // [8,2048,1024]
  const float* W = (const float*)d_in[1];    // [384,1024]
  const float* sqk = (const float*)d_in[2];  // [128]
  float* out = (float*)d_out;                // [8,2048,128]

  const size_t per = (size_t)BB * TT * DH;   // 2,097,152 elements
  US* qbf = (US*)d_ws;                       // 4 MB bf16
  US* kbf = qbf + per;                       // 4 MB
  US* vhT = kbf + per;                       // 4 MB (transposed [b][dv][t])
  US* vlT = vhT + per;                       // 4 MB
  float* pO = (float*)(vlT + per);           // 640*64*128 f32 (21 MB)
  float* pm = pO + (size_t)NJOB * BQ * DH;
  float* pl = pm + (size_t)NJOB * BQ;
  // total ws use: ~37.3 MB

  qkv_rope_norm<<<dim3(256), dim3(512), 0, stream>>>(x, W, sqk, qbf, kbf,
                                                     vhT, vlT);

  attn_causal<<<dim3(NJOB), dim3(256), SMEM_US * 2, stream>>>(
      qbf, kbf, vhT, vlT, pO, pm, pl);

  attn_merge<<<dim3((BB * TT * DH / 4) / 256), dim3(256), 0, stream>>>(
      pO, pm, pl, out);
}

// Round 5
// 215.173 us; speedup vs baseline: 1.1004x; 1.1004x over previous
//
#include <hip/hip_runtime.h>
#include <math.h>

// Problem constants
#define BB 8
#define TT 2048
#define DM 1024
#define DH 128
#define US unsigned short

typedef short s8v __attribute__((ext_vector_type(8)));
typedef US us8 __attribute__((ext_vector_type(8)));
typedef float f4v __attribute__((ext_vector_type(4)));

__device__ __forceinline__ US f2bf(float f) {
  uint u = __float_as_uint(f);
  uint r = (u + 0x7fffu + ((u >> 16) & 1u)) >> 16;  // RNE
  return (US)r;
}
__device__ __forceinline__ float bf2f(US h) {
  return __uint_as_float(((uint)h) << 16);
}
__device__ __forceinline__ void cvt4(const float4 v, uint2& h, uint2& lo) {
  US h0 = f2bf(v.x), h1 = f2bf(v.y), h2 = f2bf(v.z), h3 = f2bf(v.w);
  US l0 = f2bf(v.x - bf2f(h0)), l1 = f2bf(v.y - bf2f(h1)),
     l2 = f2bf(v.z - bf2f(h2)), l3 = f2bf(v.w - bf2f(h3));
  h = make_uint2((uint)h0 | ((uint)h1 << 16), (uint)h2 | ((uint)h3 << 16));
  lo = make_uint2((uint)l0 | ((uint)l1 << 16), (uint)l2 | ((uint)l3 << 16));
}

// ============================================================================
// Kernel 1: fused QKV projection via split-bf16 MFMA (unchanged from round 4,
// which passed).  Outputs bf16 q/k row-major, V hi/lo transposed [b][dv][t].
// ============================================================================
#define XHI 0
#define XLO 2048
#define WHI 4096
#define WLO 16384
#define NEG_L2B_64 -0.20762050593549395f  // -log2(10000)/64

__global__ __launch_bounds__(512) void qkv_rope_norm(
    const float* __restrict__ x, const float* __restrict__ W,
    const float* __restrict__ sqk, US* __restrict__ qbf, US* __restrict__ kbf,
    US* __restrict__ vhT, US* __restrict__ vlT) {
  __shared__ __align__(16) US smem_u[28672];  // 56 KB
  const int tid = threadIdx.x;
  const int m0 = blockIdx.x * 64;

  const int srow = tid >> 3;
  const int c4 = tid & 7;
  const int k8s = c4 >> 1, half = c4 & 1;
  const float* xg = x + (size_t)(m0 + srow) * DM + (c4 << 2);
  const float* wg = W + (size_t)srow * DM + (c4 << 2);
  const int xeo = (k8s * 64 + srow) * 8 + half * 4;

  const int l = tid & 63, w = tid >> 6;
  const int wm = w >> 2, wn = w & 3;
  const int lr = l & 15, k8l = l >> 4;
  const int arow = wm * 32;

  f4v acc[2][6];
#pragma unroll
  for (int r = 0; r < 2; ++r)
#pragma unroll
    for (int c = 0; c < 6; ++c) acc[r][c] = (f4v)(0.f);

  float4 gx = *(const float4*)(xg);
  float4 gw[6];
#pragma unroll
  for (int i = 0; i < 6; ++i) gw[i] = *(const float4*)(wg + (size_t)i * 64 * DM);

  for (int kc = 0; kc < 32; ++kc) {
    __syncthreads();
    {
      uint2 h, lo;
      cvt4(gx, h, lo);
      *(uint2*)&smem_u[XHI + xeo] = h;
      *(uint2*)&smem_u[XLO + xeo] = lo;
#pragma unroll
      for (int i = 0; i < 6; ++i) {
        int weo = (k8s * 384 + srow + 64 * i) * 8 + half * 4;
        cvt4(gw[i], h, lo);
        *(uint2*)&smem_u[WHI + weo] = h;
        *(uint2*)&smem_u[WLO + weo] = lo;
      }
    }
    {
      int kn = (kc < 31) ? (kc + 1) * 32 : 0;
      gx = *(const float4*)(xg + kn);
#pragma unroll
      for (int i = 0; i < 6; ++i)
        gw[i] = *(const float4*)(wg + (size_t)i * 64 * DM + kn);
    }
    __syncthreads();
    s8v axh[2], axl[2];
#pragma unroll
    for (int r = 0; r < 2; ++r) {
      int ao = (k8l * 64 + arow + r * 16 + lr) * 8;
      axh[r] = *(const s8v*)&smem_u[XHI + ao];
      axl[r] = *(const s8v*)&smem_u[XLO + ao];
    }
#pragma unroll
    for (int c = 0; c < 6; ++c) {
      int bo = (k8l * 384 + wn * 96 + c * 16 + lr) * 8;
      s8v bh = *(const s8v*)&smem_u[WHI + bo];
      s8v bl = *(const s8v*)&smem_u[WLO + bo];
#pragma unroll
      for (int r = 0; r < 2; ++r) {
        acc[r][c] =
            __builtin_amdgcn_mfma_f32_16x16x32_bf16(axh[r], bh, acc[r][c], 0, 0, 0);
        acc[r][c] =
            __builtin_amdgcn_mfma_f32_16x16x32_bf16(axl[r], bh, acc[r][c], 0, 0, 0);
        acc[r][c] =
            __builtin_amdgcn_mfma_f32_16x16x32_bf16(axh[r], bl, acc[r][c], 0, 0, 0);
      }
    }
  }

  __syncthreads();
  float* buf = (float*)smem_u;  // [64][132] floats
  const int prow = tid >> 3, sub = tid & 7;
  const int q4row = (l >> 4) * 4;
  const int bq = m0 >> 11;
  const int t0 = m0 & (TT - 1);
  const float t_pos = (float)(t0 + prow);

#pragma unroll
  for (int p = 0; p < 3; ++p) {
#pragma unroll
    for (int c = 0; c < 6; ++c) {
      int nbase = wn * 96 + c * 16;
      if ((nbase >> 7) == p) {
        int coloff = nbase & 127;
#pragma unroll
        for (int r = 0; r < 2; ++r)
#pragma unroll
          for (int q = 0; q < 4; ++q)
            buf[(arow + r * 16 + q4row + q) * 132 + coloff + lr] = acc[r][c][q];
      }
    }
    __syncthreads();
    if (p == 2) {
      const int dv = tid >> 2;
      const int rr = (tid & 3) * 16;
      us8 h0, h1, l0, l1;
#pragma unroll
      for (int i = 0; i < 8; ++i) {
        float va = buf[(rr + i) * 132 + dv];
        float vb2 = buf[(rr + 8 + i) * 132 + dv];
        US ha = f2bf(va), hb = f2bf(vb2);
        h0[i] = ha; h1[i] = hb;
        l0[i] = f2bf(va - bf2f(ha));
        l1[i] = f2bf(vb2 - bf2f(hb));
      }
      size_t base = ((size_t)bq * DH + dv) * TT + t0 + rr;
      *(us8*)(vhT + base) = h0;
      *(us8*)(vhT + base + 8) = h1;
      *(us8*)(vlT + base) = l0;
      *(us8*)(vlT + base + 8) = l1;
    } else {
      const float* br = &buf[prow * 132 + sub * 16];
      float4 a0 = *(const float4*)(br + 0);
      float4 a1 = *(const float4*)(br + 4);
      float4 a2 = *(const float4*)(br + 8);
      float4 a3 = *(const float4*)(br + 12);
      float vals[16] = {a0.x, a0.y, a0.z, a0.w, a1.x, a1.y, a1.z, a1.w,
                        a2.x, a2.y, a2.z, a2.w, a3.x, a3.y, a3.z, a3.w};
      float ov[16];
      float ss = 0.f;
#pragma unroll
      for (int j = 0; j < 16; ++j) {
        float val = vals[j];
        float partner = __shfl_xor(val, 4);
        int fi = ((sub & 3) * 16) + j;
        float ang = t_pos * exp2f((float)fi * NEG_L2B_64);
        float sn, cs;
        sincosf(ang, &sn, &cs);
        float rot = (sub < 4) ? -partner : partner;
        float o = fmaf(val, cs, rot * sn);
        ov[j] = o;
        ss = fmaf(o, o, ss);
      }
      ss += __shfl_xor(ss, 1);
      ss += __shfl_xor(ss, 2);
      ss += __shfl_xor(ss, 4);
      float rn = 1.0f / sqrtf(ss);
      const float* sqp = sqk + sub * 16;
      US* dst = (p == 0 ? qbf : kbf) + (size_t)(m0 + prow) * DH + sub * 16;
      us8 o0, o1;
#pragma unroll
      for (int j = 0; j < 8; ++j) {
        o0[j] = f2bf(ov[j] * rn * sqp[j]);
        o1[j] = f2bf(ov[8 + j] * rn * sqp[8 + j]);
      }
      *(us8*)dst = o0;
      *(us8*)(dst + 8) = o1;
    }
    __syncthreads();
  }
}

// ============================================================================
// Kernel 2: causal flash attention, bf16 MFMA, BK=32, Q-in-registers.
//   LDS = K 8KB + Vh 8KB + Vl 8KB + Ph/Pl 10.2KB = 34.2KB -> 3-4 blocks/CU
//   (occupancy now job-limited at ~2.5 blocks/CU = ~10 waves/CU, 3x round 4).
//   256 thr = 4 waves; wave w owns q-rows w*16..+15. Q frags loaded from
//   global ONCE per job (A-frag layout: row=l15, k8=l4). Per 32-wide K-tile:
//   QK^T 8 MFMA, softmax in-register, P hi/lo -> LDS (stride 40: b128 reads
//   2 lanes/bank = free), PV 24 MFMA (3-term split). 2 barriers/tile.
// ============================================================================
#define BQ 64
#define BK 32
#define SCALE 32.0f  // sqrt(d_model=1024)
#define NLOC 80
#define NJOB (NLOC * BB)

__device__ __forceinline__ int slot_base(int qt) {
  if (qt < 8) return qt;
  if (qt < 16) return 8 + 2 * (qt - 8);
  if (qt < 24) return 24 + 3 * (qt - 16);
  return 48 + 4 * (qt - 24);
}

__global__ __launch_bounds__(256) void attn_causal(
    const US* __restrict__ qbf, const US* __restrict__ kbf,
    const US* __restrict__ vhT, const US* __restrict__ vlT,
    float* __restrict__ pO, float* __restrict__ pm, float* __restrict__ pl) {
  // LDS: K [d8=16][row=32][8] us, V hi/lo [kv8=4][dv=128][8] us,
  //      P hi/lo [row=64][40] us
  __shared__ __align__(16) US sK[4096];
  __shared__ __align__(16) US sVh[4096];
  __shared__ __align__(16) US sVl[4096];
  __shared__ __align__(16) US sPh[2560];
  __shared__ __align__(16) US sPl[2560];

  const int tid = threadIdx.x;
  // ---- job decode (heavy-first; segment bounds in 32-wide tile units) ----
  const int bi = blockIdx.x;
  const int b = bi & 7;
  const int local = bi >> 3;
  int qt, s;
  if (local < 32) {
    qt = 31 - (local >> 2); s = local & 3;
  } else if (local < 56) {
    int l2 = local - 32; qt = 23 - l2 / 3; s = l2 - (l2 / 3) * 3;
  } else if (local < 72) {
    int l2 = local - 56; qt = 15 - (l2 >> 1); s = l2 & 1;
  } else {
    qt = 7 - (local - 72); s = 0;
  }
  const int S = 1 + (qt >> 3);
  const int nk = 2 * qt + 2;            // tiles of 32
  const int kt0 = (s * nk) / S;
  const int kt1 = ((s + 1) * nk) / S;
  const int slot = b * NLOC + slot_base(qt) + s;

  const int ln = tid & 63, w = tid >> 6;
  const int wrow = w * 16;
  const int l15 = ln & 15, l4 = ln >> 4;

  // ---- Q fragments straight from global (once per job) ----
  // A-frag: lane holds Q[row=wrow+l15][d=(ks*4+l4)*8 .. +7]
  s8v qf[4];
  {
    const US* qsrc =
        qbf + ((size_t)b * TT + (size_t)qt * BQ + wrow + l15) * DH + l4 * 8;
#pragma unroll
    for (int ks = 0; ks < 4; ++ks) qf[ks] = *(const s8v*)(qsrc + ks * 32);
  }

  float m[4], lsum[4];
  f4v o[8];
#pragma unroll
  for (int q = 0; q < 4; ++q) { m[q] = -1e30f; lsum[q] = 0.f; }
#pragma unroll
  for (int c8 = 0; c8 < 8; ++c8) o[c8] = (f4v)(0.f);

  for (int kt = kt0; kt < kt1; ++kt) {
    __syncthreads();  // prior tile's K/V frag reads complete
    // ---- stage K tile [16 d8][32 rows^(d8&7)][8] ----
    {
      const int d8 = tid & 15, r0 = tid >> 4;
      const US* src = kbf + ((size_t)b * TT + (size_t)kt * BK) * DH + d8 * 8;
#pragma unroll
      for (int p = 0; p < 2; ++p) {
        int r = r0 + p * 16;
        us8 v = *(const us8*)(src + (size_t)r * DH);
        *(us8*)&sK[(d8 * 32 + (r ^ (d8 & 7))) * 8] = v;
      }
    }
    // ---- stage V tiles (straight copy; pre-transposed + split) ----
    {
      const int kv8 = tid & 3, dv0 = tid >> 2;
      const size_t gb = (size_t)b * DH * TT + (size_t)kt * BK + kv8 * 8;
#pragma unroll
      for (int p = 0; p < 2; ++p) {
        int dv = dv0 + p * 64;
        us8 vh = *(const us8*)(vhT + gb + (size_t)dv * TT);
        us8 vl = *(const us8*)(vlT + gb + (size_t)dv * TT);
        *(us8*)&sVh[(kv8 * 128 + dv) * 8] = vh;
        *(us8*)&sVl[(kv8 * 128 + dv) * 8] = vl;
      }
    }
    __syncthreads();

    // ---- QK^T: 8 MFMA (2 col-frags x 4 d-slices) ----
    f4v sfr[2];
#pragma unroll
    for (int c = 0; c < 2; ++c) sfr[c] = (f4v)(0.f);
#pragma unroll
    for (int ks = 0; ks < 4; ++ks) {
      const int d8 = ks * 4 + l4;
      const int perm = (l15 ^ (d8 & 7));
      const int perm2 = ((16 + l15) ^ (d8 & 7));
      s8v bk0 = *(const s8v*)&sK[(d8 * 32 + perm) * 8];
      s8v bk1 = *(const s8v*)&sK[(d8 * 32 + perm2) * 8];
      sfr[0] = __builtin_amdgcn_mfma_f32_16x16x32_bf16(qf[ks], bk0, sfr[0], 0, 0, 0);
      sfr[1] = __builtin_amdgcn_mfma_f32_16x16x32_bf16(qf[ks], bk1, sfr[1], 0, 0, 0);
    }

    // ---- online softmax (rows wrow+l4*4+q; cols c*16+l15) + P write ----
    const bool diag = (kt >= 2 * qt);
    float alpha[4];
#pragma unroll
    for (int q = 0; q < 4; ++q) {
      const int rowg = qt * BQ + wrow + l4 * 4 + q;
      float st[2];
      float mx = -1e30f;
#pragma unroll
      for (int c = 0; c < 2; ++c) {
        float sv = sfr[c][q] * SCALE;
        if (diag && (kt * BK + c * 16 + l15 > rowg)) sv = -1e30f;
        st[c] = sv;
        mx = fmaxf(mx, sv);
      }
      mx = fmaxf(mx, __shfl_xor(mx, 1));
      mx = fmaxf(mx, __shfl_xor(mx, 2));
      mx = fmaxf(mx, __shfl_xor(mx, 4));
      mx = fmaxf(mx, __shfl_xor(mx, 8));
      float mn = fmaxf(m[q], mx);
      float a = __expf(m[q] - mn);
      float rs = 0.f;
      const int prow_off = (wrow + l4 * 4 + q) * 40 + l15;
#pragma unroll
      for (int c = 0; c < 2; ++c) {
        float pv = __expf(st[c] - mn);
        rs += pv;
        US ph = f2bf(pv);
        sPh[prow_off + c * 16] = ph;
        sPl[prow_off + c * 16] = f2bf(pv - bf2f(ph));
      }
      rs += __shfl_xor(rs, 1);
      rs += __shfl_xor(rs, 2);
      rs += __shfl_xor(rs, 4);
      rs += __shfl_xor(rs, 8);
      lsum[q] = lsum[q] * a + rs;
      m[q] = mn;
      alpha[q] = a;
    }

    // ---- rescale O, then PV (P rows wave-local: no barrier needed) ----
#pragma unroll
    for (int c8 = 0; c8 < 8; ++c8)
#pragma unroll
      for (int q = 0; q < 4; ++q) o[c8][q] *= alpha[q];

    {
      const int aoff = (wrow + l15) * 40 + l4 * 8;
      s8v pa = *(const s8v*)&sPh[aoff];
      s8v pb = *(const s8v*)&sPl[aoff];
#pragma unroll
      for (int c8 = 0; c8 < 8; ++c8) {
        const int vo = (l4 * 128 + c8 * 16 + l15) * 8;
        s8v vh = *(const s8v*)&sVh[vo];
        s8v vl = *(const s8v*)&sVl[vo];
        o[c8] = __builtin_amdgcn_mfma_f32_16x16x32_bf16(pa, vh, o[c8], 0, 0, 0);
        o[c8] = __builtin_amdgcn_mfma_f32_16x16x32_bf16(pb, vh, o[c8], 0, 0, 0);
        o[c8] = __builtin_amdgcn_mfma_f32_16x16x32_bf16(pa, vl, o[c8], 0, 0, 0);
      }
    }
  }

  // ---- epilogue: unnormalized partial O + per-row m,l ----
  float* ob = pO + (size_t)slot * (BQ * DH);
#pragma unroll
  for (int q = 0; q < 4; ++q) {
    const int r = wrow + l4 * 4 + q;
#pragma unroll
    for (int c8 = 0; c8 < 8; ++c8)
      ob[(size_t)r * DH + c8 * 16 + l15] = o[c8][q];
  }
  if (l15 == 0) {
#pragma unroll
    for (int q = 0; q < 4; ++q) {
      pm[slot * BQ + wrow + l4 * 4 + q] = m[q];
      pl[slot * BQ + wrow + l4 * 4 + q] = lsum[q];
    }
  }
}

// ============================================================================
// Kernel 3: merge partials (unchanged from round 4, which passed).
// ============================================================================
__global__ __launch_bounds__(256) void attn_merge(
    const float* __restrict__ pO, const float* __restrict__ pm,
    const float* __restrict__ pl, float* __restrict__ out) {
  const int g4 = blockIdx.x * 256 + threadIdx.x;
  const int row = g4 >> 5;
  const int c4 = g4 & 31;
  const int t = row & (TT - 1);
  const int qt = t >> 6;
  const int rloc = t & 63;
  const int b = row >> 11;
  const int S = 1 + (qt >> 3);
  const int base = b * NLOC + slot_base(qt);

  float ms[4], ls[4];
  float mstar = -1e30f;
#pragma unroll
  for (int s = 0; s < 4; ++s) {
    if (s < S) {
      ms[s] = pm[(base + s) * 64 + rloc];
      ls[s] = pl[(base + s) * 64 + rloc];
      mstar = fmaxf(mstar, ms[s]);
    }
  }
  float4 acc = make_float4(0.f, 0.f, 0.f, 0.f);
  float L = 0.f;
#pragma unroll
  for (int s = 0; s < 4; ++s) {
    if (s < S) {
      float wgt = __expf(ms[s] - mstar);
      L += wgt * ls[s];
      float4 o4 = *(const float4*)(pO + (size_t)(base + s) * (64 * DH) +
                                   (size_t)rloc * DH + (c4 << 2));
      acc.x = fmaf(wgt, o4.x, acc.x);
      acc.y = fmaf(wgt, o4.y, acc.y);
      acc.z = fmaf(wgt, o4.z, acc.z);
      acc.w = fmaf(wgt, o4.w, acc.w);
    }
  }
  float inv = 1.0f / L;
  *(float4*)(out + (size_t)row * DH + (c4 << 2)) =
      make_float4(acc.x * inv, acc.y * inv, acc.z * inv, acc.w * inv);
}

// ============================================================================
extern "C" void kernel_launch(void* const* d_in, const int* in_sizes, int n_in,
                              void* d_out, int out_size, void* d_ws, size_t ws_size,
                              hipStream_t stream) {
  const float* x = (const float*)d_in[0];    // [8,2048,1024]
  const float* W = (const float*)d_in[1];    // [384,1024]
  const float* sqk = (const float*)d_in[2];  // [128]
  float* out = (float*)d_out;                // [8,2048,128]

  const size_t per = (size_t)BB * TT * DH;   // 2,097,152 elements
  US* qbf = (US*)d_ws;                       // 4 MB bf16
  US* kbf = qbf + per;                       // 4 MB
  US* vhT = kbf + per;                       // 4 MB (transposed [b][dv][t])
  US* vlT = vhT + per;                       // 4 MB
  float* pO = (float*)(vlT + per);           // 640*64*128 f32 (21 MB)
  float* pm = pO + (size_t)NJOB * 64 * DH;
  float* pl = pm + (size_t)NJOB * 64;
  // total ws use: ~37.3 MB (same as round 4, proven to fit)

  qkv_rope_norm<<<dim3(256), dim3(512), 0, stream>>>(x, W, sqk, qbf, kbf,
                                                     vhT, vlT);

  attn_causal<<<dim3(NJOB), dim3(256), 0, stream>>>(qbf, kbf, vhT, vlT, pO,
                                                    pm, pl);

  attn_merge<<<dim3((BB * TT * DH / 4) / 256), dim3(256), 0, stream>>>(
      pO, pm, pl, out);
}